// Round 2
// baseline (108.368 us; speedup 1.0000x reference)
//
#include <hip/hip_runtime.h>
#include <hip/hip_bf16.h>
#include <math.h>

#define B 64
#define L 64
#define NPT 127
#define D 128
#define VOCAB 30000
#define LABELS 30
#define SPLIT 4
#define KP 129   // padded LDS row stride (floats) for K/V tiles

// ---------------------------------------------------------------------------
// K0: T[v][e] = bf16( sum_d emb[v][d] * Wc[d][e] )   (VOCAB x D, bf16 out)
// Wc staged in LDS; each thread computes a 4x4 tile; float4 emb loads.
// ---------------------------------------------------------------------------
__global__ __launch_bounds__(256) void k0_embWc(const float* __restrict__ emb,
                                                const float* __restrict__ Wc,
                                                __hip_bfloat16* __restrict__ T) {
  __shared__ float sW[D * D];  // 64 KB
  const int t = threadIdx.x;
  const int row0 = blockIdx.x * 32;
  {
    const float4* W4 = (const float4*)Wc;
    float4* sW4 = (float4*)sW;
#pragma unroll
    for (int i = 0; i < 16; ++i) sW4[t + 256 * i] = W4[t + 256 * i];
  }
  __syncthreads();
  const int rg = t >> 5;   // 0..7
  const int cg = t & 31;   // 0..31
  const int c0 = cg * 4;
  int rr[4];
#pragma unroll
  for (int i = 0; i < 4; ++i) {
    int g = row0 + rg * 4 + i;
    rr[i] = g < VOCAB ? g : VOCAB - 1;  // clamp reads, guard stores
  }
  const float4* e0 = (const float4*)(emb + (size_t)rr[0] * D);
  const float4* e1 = (const float4*)(emb + (size_t)rr[1] * D);
  const float4* e2 = (const float4*)(emb + (size_t)rr[2] * D);
  const float4* e3 = (const float4*)(emb + (size_t)rr[3] * D);
  const float4* sW4 = (const float4*)sW;
  float acc[4][4] = {};
#pragma unroll 4
  for (int k4 = 0; k4 < 32; ++k4) {
    float4 a0 = e0[k4], a1 = e1[k4], a2 = e2[k4], a3 = e3[k4];
    const float av0[4] = {a0.x, a0.y, a0.z, a0.w};
    const float av1[4] = {a1.x, a1.y, a1.z, a1.w};
    const float av2[4] = {a2.x, a2.y, a2.z, a2.w};
    const float av3[4] = {a3.x, a3.y, a3.z, a3.w};
#pragma unroll
    for (int j = 0; j < 4; ++j) {
      float4 w = sW4[(k4 * 4 + j) * 32 + cg];
      float b0 = av0[j], b1 = av1[j], b2 = av2[j], b3 = av3[j];
      acc[0][0] += b0 * w.x; acc[0][1] += b0 * w.y; acc[0][2] += b0 * w.z; acc[0][3] += b0 * w.w;
      acc[1][0] += b1 * w.x; acc[1][1] += b1 * w.y; acc[1][2] += b1 * w.z; acc[1][3] += b1 * w.w;
      acc[2][0] += b2 * w.x; acc[2][1] += b2 * w.y; acc[2][2] += b2 * w.z; acc[2][3] += b2 * w.w;
      acc[3][0] += b3 * w.x; acc[3][1] += b3 * w.y; acc[3][2] += b3 * w.z; acc[3][3] += b3 * w.w;
    }
  }
  union BF4 { ushort4 u; unsigned short s[4]; };
#pragma unroll
  for (int i = 0; i < 4; ++i) {
    int g = row0 + rg * 4 + i;
    if (g < VOCAB) {
      BF4 o;
#pragma unroll
      for (int j = 0; j < 4; ++j) {
        __hip_bfloat16 h = __float2bfloat16(acc[i][j]);
        o.s[j] = *(unsigned short*)&h;
      }
      *(ushort4*)&T[(size_t)g * D + c0] = o.u;
    }
  }
}

// ---------------------------------------------------------------------------
// K1a: tree-encode one (b,l) row per block. 128 threads = one feature dim
// each. Post-order streaming subtree-sum: 7-register stack, 127 gathered
// node-loads per thread, running max, relu -> enc.
// ---------------------------------------------------------------------------
__global__ __launch_bounds__(128) void k1a_tree(
    const int* __restrict__ tokens, const __hip_bfloat16* __restrict__ T,
    const float* __restrict__ bc, float* __restrict__ enc) {
  __shared__ int stok[NPT];
  const int t = threadIdx.x;  // feature dim
  const int row = blockIdx.x;
  if (t < NPT) stok[t] = tokens[(size_t)row * NPT + t];
  __syncthreads();
  const float bcd = bc[t];
  float m = -1e30f;
  float stk[6];
#pragma unroll
  for (int li = 0; li < 64; ++li) {
    float cur = __bfloat162float(T[(size_t)stok[63 + li] * D + t]) + bcd;
    m = fmaxf(m, cur);
    int x = li;
#pragma unroll
    for (int h = 0; h < 6; ++h) {
      if (!(x & 1)) break;
      int pnode = ((64 + li) >> (h + 1)) - 1;
      float pe = __bfloat162float(T[(size_t)stok[pnode] * D + t]) + bcd;
      cur = stk[h] + cur + pe;
      m = fmaxf(m, cur);
      x >>= 1;
    }
    if (li != 63) {
      // push at height = trailing-ones(li) (compile-time per li)
      int h = 0, y = li;
      while (y & 1) { ++h; y >>= 1; }
      stk[h] = cur;
    }
  }
  enc[(size_t)row * D + t] = fmaxf(m, 0.0f);
}

// ---------------------------------------------------------------------------
// K1b: q/k/v projection GEMM. enc(4096x128) @ W(128x128) for each of
// Wq/Wk/Wv (one col-block each). 256 threads, 4x4 micro-tiles, 32-row blocks.
// ---------------------------------------------------------------------------
__global__ __launch_bounds__(256) void k1b_qkv(
    const float* __restrict__ enc, const float* __restrict__ Wq,
    const float* __restrict__ Wk, const float* __restrict__ Wv,
    float* __restrict__ qb, float* __restrict__ kb, float* __restrict__ vb) {
  __shared__ float sE[32 * D];  // 16 KB
  const int t = threadIdx.x;
  const int rb = blockIdx.x / 3;
  const int cb = blockIdx.x % 3;
  const int r0 = rb * 32;
  const float* W = cb == 0 ? Wq : (cb == 1 ? Wk : Wv);
  float* outb = cb == 0 ? qb : (cb == 1 ? kb : vb);
  {
    const float4* E4 = (const float4*)(enc + (size_t)r0 * D);
    float4* sE4 = (float4*)sE;
#pragma unroll
    for (int i = 0; i < 4; ++i) sE4[t + 256 * i] = E4[t + 256 * i];
  }
  __syncthreads();
  const int rg = t >> 5;
  const int cg = t & 31;
  float acc[4][4] = {};
#pragma unroll 4
  for (int k = 0; k < D; ++k) {
    float4 w = *(const float4*)&W[k * D + cg * 4];
    float e0 = sE[(rg * 4 + 0) * D + k];
    float e1 = sE[(rg * 4 + 1) * D + k];
    float e2 = sE[(rg * 4 + 2) * D + k];
    float e3 = sE[(rg * 4 + 3) * D + k];
    acc[0][0] += e0 * w.x; acc[0][1] += e0 * w.y; acc[0][2] += e0 * w.z; acc[0][3] += e0 * w.w;
    acc[1][0] += e1 * w.x; acc[1][1] += e1 * w.y; acc[1][2] += e1 * w.z; acc[1][3] += e1 * w.w;
    acc[2][0] += e2 * w.x; acc[2][1] += e2 * w.y; acc[2][2] += e2 * w.z; acc[2][3] += e2 * w.w;
    acc[3][0] += e3 * w.x; acc[3][1] += e3 * w.y; acc[3][2] += e3 * w.z; acc[3][3] += e3 * w.w;
  }
#pragma unroll
  for (int i = 0; i < 4; ++i) {
    float4 o = make_float4(acc[i][0], acc[i][1], acc[i][2], acc[i][3]);
    *(float4*)&outb[(size_t)(r0 + rg * 4 + i) * D + cg * 4] = o;
  }
}

// ---------------------------------------------------------------------------
// K2: attention for one (batch, split of 16 q-rows). 512 threads = 8 waves,
// 2 q-rows per wave. K/V staged in LDS (78 KB -> 2 blocks/CU); Wo from L2.
// ---------------------------------------------------------------------------
__global__ __launch_bounds__(512) void k2_attn(
    const float* __restrict__ qb, const float* __restrict__ kb,
    const float* __restrict__ vb, const int* __restrict__ mask,
    const float* __restrict__ Wo, float* __restrict__ pool) {
  __shared__ float sK[L * KP];      // 33 KB
  __shared__ float sV[L * KP];      // 33 KB
  __shared__ float sQ[8][D];
  __shared__ float sOr[8][D];
  __shared__ float sPool[8][D];
  const int t = threadIdx.x;
  const int w = t >> 6, lane = t & 63;
  const int b = blockIdx.x / SPLIT;
  const int sp = blockIdx.x % SPLIT;
  for (int i = t; i < L * D; i += 512) {
    int r = i >> 7, c = i & 127;
    sK[r * KP + c] = kb[(size_t)(b * L + r) * D + c];
    sV[r * KP + c] = vb[(size_t)(b * L + r) * D + c];
  }
  __syncthreads();
  float pm0 = -1e30f, pm1 = -1e30f;
#pragma unroll
  for (int it = 0; it < 2; ++it) {
    const int r = sp * 16 + w * 2 + it;
    float2 qv = *(const float2*)&qb[(size_t)(b * L + r) * D + lane * 2];
    sQ[w][lane * 2] = qv.x;
    sQ[w][lane * 2 + 1] = qv.y;
    __syncthreads();
    float sc = 0.f;
#pragma unroll 8
    for (int k = 0; k < D; ++k) sc += sQ[w][k] * sK[lane * KP + k];
    sc *= 0.08838834764831845f;  // 1/sqrt(128)
    if (mask[((size_t)b * L + r) * L + lane] <= 0) sc = -1e9f;
    float mx = sc;
#pragma unroll
    for (int off = 32; off >= 1; off >>= 1) mx = fmaxf(mx, __shfl_xor(mx, off));
    float ex = __expf(sc - mx);
    float sm = ex;
#pragma unroll
    for (int off = 32; off >= 1; off >>= 1) sm += __shfl_xor(sm, off);
    float a = ex / sm;
    float o0 = 0.f, o1 = 0.f;
#pragma unroll
    for (int j = 0; j < L; ++j) {
      float aj = __shfl(a, j);
      o0 += aj * sV[j * KP + lane];
      o1 += aj * sV[j * KP + lane + 64];
    }
    sOr[w][lane] = o0;
    sOr[w][lane + 64] = o1;
    __syncthreads();
    float p0 = 0.f, p1 = 0.f;
#pragma unroll 4
    for (int d = 0; d < D; ++d) {
      float od = sOr[w][d];
      p0 += od * Wo[d * D + lane];
      p1 += od * Wo[d * D + lane + 64];
    }
    pm0 = fmaxf(pm0, p0);
    pm1 = fmaxf(pm1, p1);
    __syncthreads();  // protect sQ/sOr reuse next iteration
  }
  sPool[w][lane] = pm0;
  sPool[w][lane + 64] = pm1;
  __syncthreads();
  if (t < D) {
    float pv = sPool[0][t];
#pragma unroll
    for (int i = 1; i < 8; ++i) pv = fmaxf(pv, sPool[i][t]);
    pool[(size_t)blockIdx.x * D + t] = pv;
  }
}

// ---------------------------------------------------------------------------
// K3: final pooled max over splits + logits
// ---------------------------------------------------------------------------
__global__ __launch_bounds__(128) void k3_logits(const float* __restrict__ pool,
                                                 const float* __restrict__ Wl,
                                                 const float* __restrict__ bl,
                                                 float* __restrict__ out) {
  __shared__ float sP[D];
  const int b = blockIdx.x, t = threadIdx.x;
  float pv = pool[((size_t)b * SPLIT) * D + t];
#pragma unroll
  for (int i = 1; i < SPLIT; ++i)
    pv = fmaxf(pv, pool[((size_t)b * SPLIT + i) * D + t]);
  sP[t] = pv;
  __syncthreads();
  if (t < LABELS) {
    float a = bl[t];
#pragma unroll 4
    for (int d = 0; d < D; ++d) a += sP[d] * Wl[d * LABELS + t];
    out[b * LABELS + t] = a;
  }
}

extern "C" void kernel_launch(void* const* d_in, const int* in_sizes, int n_in,
                              void* d_out, int out_size, void* d_ws, size_t ws_size,
                              hipStream_t stream) {
  const int* tokens = (const int*)d_in[0];
  const int* mask = (const int*)d_in[1];
  const float* emb = (const float*)d_in[2];
  const float* Wc = (const float*)d_in[3];
  const float* bc = (const float*)d_in[4];
  const float* Wq = (const float*)d_in[5];
  const float* Wk = (const float*)d_in[6];
  const float* Wv = (const float*)d_in[7];
  const float* Wo = (const float*)d_in[8];
  const float* Wl = (const float*)d_in[9];
  const float* bl = (const float*)d_in[10];
  float* out = (float*)d_out;

  __hip_bfloat16* T = (__hip_bfloat16*)d_ws;        // VOCAB*D bf16 = 7.68 MB
  float* enc = (float*)(T + (size_t)VOCAB * D);     // B*L*D f32 = 2 MB
  float* qb = enc + (size_t)B * L * D;
  float* kb = qb + (size_t)B * L * D;
  float* vb = kb + (size_t)B * L * D;
  float* pool = vb + (size_t)B * L * D;             // B*SPLIT*D

  hipLaunchKernelGGL(k0_embWc, dim3((VOCAB + 31) / 32), dim3(256), 0, stream,
                     emb, Wc, T);
  hipLaunchKernelGGL(k1a_tree, dim3(B * L), dim3(128), 0, stream,
                     tokens, T, bc, enc);
  hipLaunchKernelGGL(k1b_qkv, dim3((B * L / 32) * 3), dim3(256), 0, stream,
                     enc, Wq, Wk, Wv, qb, kb, vb);
  hipLaunchKernelGGL(k2_attn, dim3(B * SPLIT), dim3(512), 0, stream,
                     qb, kb, vb, mask, Wo, pool);
  hipLaunchKernelGGL(k3_logits, dim3(B), dim3(128), 0, stream,
                     pool, Wl, bl, out);
}

// Round 3
// 108.093 us; speedup vs baseline: 1.0025x; 1.0025x over previous
//
#include <hip/hip_runtime.h>
#include <hip/hip_bf16.h>
#include <math.h>

#define B 64
#define L 64
#define NPT 127
#define D 128
#define VOCAB 30000
#define LABELS 30
#define SPLIT 4
#define KP 129   // padded LDS row stride (floats) for K/V tiles

typedef __attribute__((ext_vector_type(4))) unsigned int uint4v;

__device__ __forceinline__ float bfhi(unsigned int u) {  // high ushort -> f32
  unsigned int x = u & 0xffff0000u;
  return __builtin_bit_cast(float, x);
}
__device__ __forceinline__ float bflo(unsigned int u) {  // low ushort -> f32
  unsigned int x = u << 16;
  return __builtin_bit_cast(float, x);
}

// ---------------------------------------------------------------------------
// K0: T[v][e] = bf16( sum_d emb[v][d] * Wc[d][e] )   (VOCAB x D, bf16 out)
// ---------------------------------------------------------------------------
__global__ __launch_bounds__(256) void k0_embWc(const float* __restrict__ emb,
                                                const float* __restrict__ Wc,
                                                __hip_bfloat16* __restrict__ T) {
  __shared__ float sW[D * D];  // 64 KB
  const int t = threadIdx.x;
  const int row0 = blockIdx.x * 32;
  {
    const float4* W4 = (const float4*)Wc;
    float4* sW4 = (float4*)sW;
#pragma unroll
    for (int i = 0; i < 16; ++i) sW4[t + 256 * i] = W4[t + 256 * i];
  }
  __syncthreads();
  const int rg = t >> 5;   // 0..7
  const int cg = t & 31;   // 0..31
  const int c0 = cg * 4;
  int rr[4];
#pragma unroll
  for (int i = 0; i < 4; ++i) {
    int g = row0 + rg * 4 + i;
    rr[i] = g < VOCAB ? g : VOCAB - 1;  // clamp reads, guard stores
  }
  const float4* e0 = (const float4*)(emb + (size_t)rr[0] * D);
  const float4* e1 = (const float4*)(emb + (size_t)rr[1] * D);
  const float4* e2 = (const float4*)(emb + (size_t)rr[2] * D);
  const float4* e3 = (const float4*)(emb + (size_t)rr[3] * D);
  const float4* sW4 = (const float4*)sW;
  float acc[4][4] = {};
#pragma unroll 4
  for (int k4 = 0; k4 < 32; ++k4) {
    float4 a0 = e0[k4], a1 = e1[k4], a2 = e2[k4], a3 = e3[k4];
    const float av0[4] = {a0.x, a0.y, a0.z, a0.w};
    const float av1[4] = {a1.x, a1.y, a1.z, a1.w};
    const float av2[4] = {a2.x, a2.y, a2.z, a2.w};
    const float av3[4] = {a3.x, a3.y, a3.z, a3.w};
#pragma unroll
    for (int j = 0; j < 4; ++j) {
      float4 w = sW4[(k4 * 4 + j) * 32 + cg];
      float b0 = av0[j], b1 = av1[j], b2 = av2[j], b3 = av3[j];
      acc[0][0] += b0 * w.x; acc[0][1] += b0 * w.y; acc[0][2] += b0 * w.z; acc[0][3] += b0 * w.w;
      acc[1][0] += b1 * w.x; acc[1][1] += b1 * w.y; acc[1][2] += b1 * w.z; acc[1][3] += b1 * w.w;
      acc[2][0] += b2 * w.x; acc[2][1] += b2 * w.y; acc[2][2] += b2 * w.z; acc[2][3] += b2 * w.w;
      acc[3][0] += b3 * w.x; acc[3][1] += b3 * w.y; acc[3][2] += b3 * w.z; acc[3][3] += b3 * w.w;
    }
  }
  union BF4 { ushort4 u; unsigned short s[4]; };
#pragma unroll
  for (int i = 0; i < 4; ++i) {
    int g = row0 + rg * 4 + i;
    if (g < VOCAB) {
      BF4 o;
#pragma unroll
      for (int j = 0; j < 4; ++j) {
        __hip_bfloat16 h = __float2bfloat16(acc[i][j]);
        o.s[j] = *(unsigned short*)&h;
      }
      *(ushort4*)&T[(size_t)g * D + c0] = o.u;
    }
  }
}

// ---------------------------------------------------------------------------
// K1a: tree-encode one (b,l) row per block, 512 threads.
// Phase 1 (transposed gather): thread loads 16B = 8 dims of one node;
// 32 nodes per pass x 4 passes -> e[node][dim] f32 in LDS (+bc folded in).
// Phase 2: threads 0..127 (dim each) run streaming post-order subtree-sum
// over LDS, running max, relu -> enc.
// ---------------------------------------------------------------------------
__global__ __launch_bounds__(512) void k1a_tree(
    const int* __restrict__ tokens, const __hip_bfloat16* __restrict__ T,
    const float* __restrict__ bc, float* __restrict__ enc) {
  __shared__ float e[128][D];  // 64 KB (row 127 = pad)
  __shared__ int stok[128];
  __shared__ float sbc[D];
  const int t = threadIdx.x;
  const int row = blockIdx.x;
  if (t < 128) {
    stok[t] = (t < NPT) ? tokens[(size_t)row * NPT + t] : 0;
    sbc[t] = bc[t];
  }
  __syncthreads();
  const int nd = t >> 4;    // 0..31: node within pass
  const int sub = t & 15;   // 16B chunk within row
#pragma unroll
  for (int p = 0; p < 4; ++p) {
    const int node = p * 32 + nd;
    const int tok = stok[node];
    uint4v v = *(const uint4v*)(T + (size_t)tok * D + sub * 8);
    const int d0 = sub * 8;
    e[node][d0 + 0] = bflo(v.x) + sbc[d0 + 0];
    e[node][d0 + 1] = bfhi(v.x) + sbc[d0 + 1];
    e[node][d0 + 2] = bflo(v.y) + sbc[d0 + 2];
    e[node][d0 + 3] = bfhi(v.y) + sbc[d0 + 3];
    e[node][d0 + 4] = bflo(v.z) + sbc[d0 + 4];
    e[node][d0 + 5] = bfhi(v.z) + sbc[d0 + 5];
    e[node][d0 + 6] = bflo(v.w) + sbc[d0 + 6];
    e[node][d0 + 7] = bfhi(v.w) + sbc[d0 + 7];
  }
  __syncthreads();
  if (t < 128) {
    const int d = t;
    float m = -1e30f;
    float stk[6];
#pragma unroll
    for (int li = 0; li < 64; ++li) {
      float cur = e[63 + li][d];
      m = fmaxf(m, cur);
      int x = li;
#pragma unroll
      for (int h = 0; h < 6; ++h) {
        if (!(x & 1)) break;
        int pnode = ((64 + li) >> (h + 1)) - 1;
        cur = stk[h] + cur + e[pnode][d];
        m = fmaxf(m, cur);
        x >>= 1;
      }
      if (li != 63) {
        int h = 0, y = li;
        while (y & 1) { ++h; y >>= 1; }
        stk[h] = cur;
      }
    }
    enc[(size_t)row * D + d] = fmaxf(m, 0.0f);
  }
}

// ---------------------------------------------------------------------------
// K1b: q/k/v projection GEMM. enc(4096x128) @ W(128x128) for Wq/Wk/Wv.
// ---------------------------------------------------------------------------
__global__ __launch_bounds__(256) void k1b_qkv(
    const float* __restrict__ enc, const float* __restrict__ Wq,
    const float* __restrict__ Wk, const float* __restrict__ Wv,
    float* __restrict__ qb, float* __restrict__ kb, float* __restrict__ vb) {
  __shared__ float sE[32 * D];  // 16 KB
  const int t = threadIdx.x;
  const int rb = blockIdx.x / 3;
  const int cb = blockIdx.x % 3;
  const int r0 = rb * 32;
  const float* W = cb == 0 ? Wq : (cb == 1 ? Wk : Wv);
  float* outb = cb == 0 ? qb : (cb == 1 ? kb : vb);
  {
    const float4* E4 = (const float4*)(enc + (size_t)r0 * D);
    float4* sE4 = (float4*)sE;
#pragma unroll
    for (int i = 0; i < 4; ++i) sE4[t + 256 * i] = E4[t + 256 * i];
  }
  __syncthreads();
  const int rg = t >> 5;
  const int cg = t & 31;
  float acc[4][4] = {};
#pragma unroll 4
  for (int k = 0; k < D; ++k) {
    float4 w = *(const float4*)&W[k * D + cg * 4];
    float e0 = sE[(rg * 4 + 0) * D + k];
    float e1 = sE[(rg * 4 + 1) * D + k];
    float e2 = sE[(rg * 4 + 2) * D + k];
    float e3 = sE[(rg * 4 + 3) * D + k];
    acc[0][0] += e0 * w.x; acc[0][1] += e0 * w.y; acc[0][2] += e0 * w.z; acc[0][3] += e0 * w.w;
    acc[1][0] += e1 * w.x; acc[1][1] += e1 * w.y; acc[1][2] += e1 * w.z; acc[1][3] += e1 * w.w;
    acc[2][0] += e2 * w.x; acc[2][1] += e2 * w.y; acc[2][2] += e2 * w.z; acc[2][3] += e2 * w.w;
    acc[3][0] += e3 * w.x; acc[3][1] += e3 * w.y; acc[3][2] += e3 * w.z; acc[3][3] += e3 * w.w;
  }
#pragma unroll
  for (int i = 0; i < 4; ++i) {
    float4 o = make_float4(acc[i][0], acc[i][1], acc[i][2], acc[i][3]);
    *(float4*)&outb[(size_t)(r0 + rg * 4 + i) * D + cg * 4] = o;
  }
}

// ---------------------------------------------------------------------------
// K2: attention for one (batch, split of 16 q-rows). 512 threads = 8 waves,
// 2 q-rows per wave. K/V staged in LDS. Writes pre-Wo out rows to ob.
// ---------------------------------------------------------------------------
__global__ __launch_bounds__(512) void k2_attn(
    const float* __restrict__ qb, const float* __restrict__ kb,
    const float* __restrict__ vb, const int* __restrict__ mask,
    float* __restrict__ ob) {
  __shared__ float sK[L * KP];      // 33 KB
  __shared__ float sV[L * KP];      // 33 KB
  __shared__ float sQ[8][D];
  const int t = threadIdx.x;
  const int w = t >> 6, lane = t & 63;
  const int b = blockIdx.x / SPLIT;
  const int sp = blockIdx.x % SPLIT;
  for (int i = t * 4; i < L * D; i += 512 * 4) {
    int r = i >> 7, c = i & 127;
    float4 kv = *(const float4*)&kb[(size_t)(b * L + r) * D + c];
    float4 vv = *(const float4*)&vb[(size_t)(b * L + r) * D + c];
    sK[r * KP + c] = kv.x; sK[r * KP + c + 1] = kv.y;
    sK[r * KP + c + 2] = kv.z; sK[r * KP + c + 3] = kv.w;
    sV[r * KP + c] = vv.x; sV[r * KP + c + 1] = vv.y;
    sV[r * KP + c + 2] = vv.z; sV[r * KP + c + 3] = vv.w;
  }
  __syncthreads();
#pragma unroll
  for (int it = 0; it < 2; ++it) {
    const int r = sp * 16 + w * 2 + it;
    float2 qv = *(const float2*)&qb[(size_t)(b * L + r) * D + lane * 2];
    sQ[w][lane * 2] = qv.x;
    sQ[w][lane * 2 + 1] = qv.y;
    // wave-private buffer: no block sync needed (lgkm ordering within wave)
    float sc = 0.f;
#pragma unroll 8
    for (int k = 0; k < D; ++k) sc += sQ[w][k] * sK[lane * KP + k];
    sc *= 0.08838834764831845f;  // 1/sqrt(128)
    if (mask[((size_t)b * L + r) * L + lane] <= 0) sc = -1e9f;
    float mx = sc;
#pragma unroll
    for (int off = 32; off >= 1; off >>= 1) mx = fmaxf(mx, __shfl_xor(mx, off));
    float ex = __expf(sc - mx);
    float sm = ex;
#pragma unroll
    for (int off = 32; off >= 1; off >>= 1) sm += __shfl_xor(sm, off);
    float a = ex / sm;
    float o0 = 0.f, o1 = 0.f;
#pragma unroll
    for (int j = 0; j < L; ++j) {
      float aj = __shfl(a, j);
      o0 += aj * sV[j * KP + lane];
      o1 += aj * sV[j * KP + lane + 64];
    }
    ob[(size_t)(b * L + r) * D + lane] = o0;
    ob[(size_t)(b * L + r) * D + lane + 64] = o1;
  }
}

// ---------------------------------------------------------------------------
// K2b: out2 = ob(4096x128) @ Wo(128x128)
// ---------------------------------------------------------------------------
__global__ __launch_bounds__(256) void k2b_proj(
    const float* __restrict__ ob, const float* __restrict__ Wo,
    float* __restrict__ out2) {
  __shared__ float sE[32 * D];  // 16 KB
  const int t = threadIdx.x;
  const int r0 = blockIdx.x * 32;
  {
    const float4* E4 = (const float4*)(ob + (size_t)r0 * D);
    float4* sE4 = (float4*)sE;
#pragma unroll
    for (int i = 0; i < 4; ++i) sE4[t + 256 * i] = E4[t + 256 * i];
  }
  __syncthreads();
  const int rg = t >> 5;
  const int cg = t & 31;
  float acc[4][4] = {};
#pragma unroll 4
  for (int k = 0; k < D; ++k) {
    float4 w = *(const float4*)&Wo[k * D + cg * 4];
    float e0 = sE[(rg * 4 + 0) * D + k];
    float e1 = sE[(rg * 4 + 1) * D + k];
    float e2 = sE[(rg * 4 + 2) * D + k];
    float e3 = sE[(rg * 4 + 3) * D + k];
    acc[0][0] += e0 * w.x; acc[0][1] += e0 * w.y; acc[0][2] += e0 * w.z; acc[0][3] += e0 * w.w;
    acc[1][0] += e1 * w.x; acc[1][1] += e1 * w.y; acc[1][2] += e1 * w.z; acc[1][3] += e1 * w.w;
    acc[2][0] += e2 * w.x; acc[2][1] += e2 * w.y; acc[2][2] += e2 * w.z; acc[2][3] += e2 * w.w;
    acc[3][0] += e3 * w.x; acc[3][1] += e3 * w.y; acc[3][2] += e3 * w.z; acc[3][3] += e3 * w.w;
  }
#pragma unroll
  for (int i = 0; i < 4; ++i) {
    float4 o = make_float4(acc[i][0], acc[i][1], acc[i][2], acc[i][3]);
    *(float4*)&out2[(size_t)(r0 + rg * 4 + i) * D + cg * 4] = o;
  }
}

// ---------------------------------------------------------------------------
// K3: per batch: pooled max over L rows of out2, then logits
// ---------------------------------------------------------------------------
__global__ __launch_bounds__(128) void k3_logits(const float* __restrict__ out2,
                                                 const float* __restrict__ Wl,
                                                 const float* __restrict__ bl,
                                                 float* __restrict__ out) {
  __shared__ float sP[D];
  const int b = blockIdx.x, t = threadIdx.x;
  float pv = -1e30f;
#pragma unroll 8
  for (int r = 0; r < L; ++r)
    pv = fmaxf(pv, out2[(size_t)(b * L + r) * D + t]);
  sP[t] = pv;
  __syncthreads();
  if (t < LABELS) {
    float a = bl[t];
#pragma unroll 4
    for (int d = 0; d < D; ++d) a += sP[d] * Wl[d * LABELS + t];
    out[b * LABELS + t] = a;
  }
}

extern "C" void kernel_launch(void* const* d_in, const int* in_sizes, int n_in,
                              void* d_out, int out_size, void* d_ws, size_t ws_size,
                              hipStream_t stream) {
  const int* tokens = (const int*)d_in[0];
  const int* mask = (const int*)d_in[1];
  const float* emb = (const float*)d_in[2];
  const float* Wc = (const float*)d_in[3];
  const float* bc = (const float*)d_in[4];
  const float* Wq = (const float*)d_in[5];
  const float* Wk = (const float*)d_in[6];
  const float* Wv = (const float*)d_in[7];
  const float* Wo = (const float*)d_in[8];
  const float* Wl = (const float*)d_in[9];
  const float* bl = (const float*)d_in[10];
  float* out = (float*)d_out;

  __hip_bfloat16* T = (__hip_bfloat16*)d_ws;        // VOCAB*D bf16 = 7.68 MB
  float* enc = (float*)(T + (size_t)VOCAB * D);     // B*L*D f32 = 2 MB each
  float* qb = enc + (size_t)B * L * D;
  float* kb = qb + (size_t)B * L * D;
  float* vb = kb + (size_t)B * L * D;
  float* obuf = vb + (size_t)B * L * D;
  float* out2 = obuf + (size_t)B * L * D;

  hipLaunchKernelGGL(k0_embWc, dim3((VOCAB + 31) / 32), dim3(256), 0, stream,
                     emb, Wc, T);
  hipLaunchKernelGGL(k1a_tree, dim3(B * L), dim3(512), 0, stream,
                     tokens, T, bc, enc);
  hipLaunchKernelGGL(k1b_qkv, dim3((B * L / 32) * 3), dim3(256), 0, stream,
                     enc, Wq, Wk, Wv, qb, kb, vb);
  hipLaunchKernelGGL(k2_attn, dim3(B * SPLIT), dim3(512), 0, stream,
                     qb, kb, vb, mask, obuf);
  hipLaunchKernelGGL(k2b_proj, dim3(B * L / 32), dim3(256), 0, stream,
                     obuf, Wo, out2);
  hipLaunchKernelGGL(k3_logits, dim3(B), dim3(128), 0, stream,
                     out2, Wl, bl, out);
}